// Round 3
// baseline (1698.120 us; speedup 1.0000x reference)
//
#include <hip/hip_runtime.h>
#include <cstdint>
#include <cstddef>

// Problem constants (fixed shapes from the reference)
#define D_MODEL 2048
#define T_SEQ   2048
#define N_BATCH 4
#define N_HEAD  16
#define HD      128
#define M_ROWS  (N_BATCH * T_SEQ)   // 8192
#define N_QKV   (3 * D_MODEL)       // 6144

typedef short          s8x  __attribute__((ext_vector_type(8)));   // 8 x bf16 (4 VGPRs)
typedef float          f4x  __attribute__((ext_vector_type(4)));
typedef float          f4v  __attribute__((ext_vector_type(4)));
typedef unsigned short u16;
typedef u16            u16x8 __attribute__((ext_vector_type(8)));

// fp32 -> bf16, round-to-nearest-even
__device__ __forceinline__ u16 f2bf(float f) {
    union { float f; unsigned u; } v; v.f = f;
    unsigned r = (v.u + 0x7FFFu + ((v.u >> 16) & 1u)) >> 16;
    return (u16)r;
}

// async global->LDS, 16B per lane (GEMM staging only)
__device__ __forceinline__ void glds16(const void* g, void* l) {
    __builtin_amdgcn_global_load_lds(
        (const __attribute__((address_space(1))) void*)g,
        (__attribute__((address_space(3))) void*)l, 16, 0, 0);
}

// DPP row_ror butterfly step: lane i of each 16-lane row reads lane (i+N)&15
template<int CTRL>
__device__ __forceinline__ float dppror(float v) {
    int i = __builtin_bit_cast(int, v);
    int r = __builtin_amdgcn_update_dpp(i, i, CTRL, 0xf, 0xf, true);
    return __builtin_bit_cast(float, r);
}
// max over the 16 lanes of a DPP row, result broadcast to all 16
__device__ __forceinline__ float rowmax16(float v) {
    v = fmaxf(v, dppror<0x128>(v));   // row_ror:8
    v = fmaxf(v, dppror<0x124>(v));   // row_ror:4
    v = fmaxf(v, dppror<0x122>(v));   // row_ror:2
    v = fmaxf(v, dppror<0x121>(v));   // row_ror:1
    return v;
}

// ---------------------------------------------------------------------------
// fp32 -> bf16 bulk convert (8 elements / thread / iter)
// ---------------------------------------------------------------------------
__global__ void cvt_f32_bf16(const float* __restrict__ in, u16* __restrict__ out, int n8) {
    int i = blockIdx.x * blockDim.x + threadIdx.x;
    int stride = gridDim.x * blockDim.x;
    for (; i < n8; i += stride) {
        f4v a = reinterpret_cast<const f4v*>(in)[2 * i];
        f4v b = reinterpret_cast<const f4v*>(in)[2 * i + 1];
        u16x8 o;
        o[0] = f2bf(a[0]); o[1] = f2bf(a[1]); o[2] = f2bf(a[2]); o[3] = f2bf(a[3]);
        o[4] = f2bf(b[0]); o[5] = f2bf(b[1]); o[6] = f2bf(b[2]); o[7] = f2bf(b[3]);
        reinterpret_cast<u16x8*>(out)[i] = o;
    }
}

// ---------------------------------------------------------------------------
// C[m][n] = (sum_k A[m][k]*B[n][k] + bias[n]) * (col<qcols ? qscale : 1)
// (B^T layout, m97 structure) 128x128 tile, BK=32, 4 waves, 4x4 16x16 frags.
// ---------------------------------------------------------------------------
template<bool OUT_BF16>
__global__ __launch_bounds__(256)
void gemm_bt(const u16* __restrict__ A, const u16* __restrict__ B,
             const float* __restrict__ bias, void* __restrict__ C,
             int M, int N, int K, int nbn, float qscale, int qcols) {
    __shared__ u16 As[128 * 32];
    __shared__ u16 Bs[128 * 32];

    int nwg = gridDim.x;
    int wg  = blockIdx.x;
    int qx  = nwg >> 3;                 // nwg % 8 == 0 by construction
    wg = (wg & 7) * qx + (wg >> 3);     // XCD-aware swizzle
    int bm = wg / nbn, bn = wg % nbn;

    int t   = threadIdx.x;
    int wid = t >> 6;
    int l15 = t & 15, l4 = (t >> 4) & 3;
    int wr  = wid >> 1, wc = wid & 1;

    f4x acc[4][4] = {};

    const u16* ga = A + (size_t)(bm * 128 + (t >> 2)) * K + (t & 3) * 8;
    const u16* gb = B + (size_t)(bn * 128 + (t >> 2)) * K + (t & 3) * 8;
    char* lA = (char*)As + wid * 1024;
    char* lB = (char*)Bs + wid * 1024;

    for (int k0 = 0; k0 < K; k0 += 32) {
        glds16(ga,              lA);
        glds16(ga + 64 * (size_t)K, lA + 4096);
        glds16(gb,              lB);
        glds16(gb + 64 * (size_t)K, lB + 4096);
        ga += 32; gb += 32;
        __syncthreads();

        s8x af[4], bfr[4];
        #pragma unroll
        for (int m = 0; m < 4; m++) {
            af[m]  = *reinterpret_cast<const s8x*>(As + (wr * 64 + m * 16 + l15) * 32 + l4 * 8);
            bfr[m] = *reinterpret_cast<const s8x*>(Bs + (wc * 64 + m * 16 + l15) * 32 + l4 * 8);
        }
        #pragma unroll
        for (int m = 0; m < 4; m++)
            #pragma unroll
            for (int n = 0; n < 4; n++)
                acc[m][n] = __builtin_amdgcn_mfma_f32_16x16x32_bf16(af[m], bfr[n], acc[m][n], 0, 0, 0);
        __syncthreads();
    }

    int row0 = bm * 128 + wr * 64;
    int col0 = bn * 128 + wc * 64;
    #pragma unroll
    for (int n = 0; n < 4; n++) {
        int col = col0 + n * 16 + l15;
        float bv = bias[col];
        float sc = (col < qcols) ? qscale : 1.0f;
        #pragma unroll
        for (int m = 0; m < 4; m++) {
            #pragma unroll
            for (int r = 0; r < 4; r++) {
                int row = row0 + m * 16 + l4 * 4 + r;
                float v = (acc[m][n][r] + bv) * sc;
                if (OUT_BF16) ((u16*)C)[(size_t)row * N + col]   = f2bf(v);
                else          ((float*)C)[(size_t)row * N + col] = v;
            }
        }
    }
}

// ---------------------------------------------------------------------------
// Flash attention v3. Grid = 64 (b*h) x 16 q-blocks. 256 threads = 4 waves.
// Q-tile 128 rows (32/wave in regs), KV-tile 64.
//  - K fragments read DIRECTLY from global (L2-resident)
//  - V issued-early per tile, reg-held across both barriers, SINGLE-buffered
//    Vt with 16B-slot XOR swizzle (slot ^ row&7): LDS 33 KB -> 4 blocks/CU
//  - Pl per-wave, same XOR swizzle (kills the 8-way b128 read conflicts
//    the old +72 padding left in place)
//  - defer-max (T13, THR=8): skip acc rescale when max doesn't grow
//  - barrier schedule: QK -> B2 -> softmax+P -> PV -> B1 -> V-transpose
// ---------------------------------------------------------------------------
__global__ __launch_bounds__(256, 4)
void attn(const u16* __restrict__ qkv, const int* __restrict__ mask,
          u16* __restrict__ att) {
    __shared__ u16  Vt[128 * 64];      // 16 KB, transposed V, XOR-swizzled slots
    __shared__ u16  Pl[4][32 * 64];    // 16 KB, per-wave P tile, XOR-swizzled
    __shared__ float mbuf[2][64];      // mask bias, double-buffered (512 B)

    int wg = blockIdx.x;               // 1024
    int q8 = gridDim.x >> 3;
    wg = (wg & 7) * q8 + (wg >> 3);    // XCD swizzle
    int bh = wg >> 4;
    int qb = wg & 15;
    int b  = bh >> 4, h = bh & 15;

    int t = threadIdx.x, wid = t >> 6;
    int lane = t & 63, l15 = lane & 15, l4 = lane >> 4;

    const size_t rs = N_QKV;           // 6144 qkv row stride
    const u16* qbase = qkv + (size_t)(b * T_SEQ) * rs;
    const u16* kbase = qbase + D_MODEL + h * HD;
    const u16* vbase = qbase + 2 * D_MODEL + h * HD;

    // Q fragments in registers (pre-scaled by 1/sqrt(d)*log2e in GEMM1)
    s8x qf[2][4];
    #pragma unroll
    for (int ms = 0; ms < 2; ms++)
        #pragma unroll
        for (int kk = 0; kk < 4; kk++) {
            int row = qb * 128 + wid * 32 + ms * 16 + l15;
            qf[ms][kk] = *reinterpret_cast<const s8x*>(
                qbase + (size_t)row * rs + h * HD + kk * 32 + l4 * 8);
        }

    f4x acc[2][8] = {};
    float mrun[2][4], lrun[2][4];
    #pragma unroll
    for (int ms = 0; ms < 2; ms++)
        #pragma unroll
        for (int r = 0; r < 4; r++) { mrun[ms][r] = -__builtin_inff(); lrun[ms][r] = 0.f; }

    int vp = t & 31;    // key pair index (k = 2vp, 2vp+1)
    int vs = t >> 5;    // d slot (d0 = vs*16)
    u16* Pw = Pl[wid];

    // ---- prologue: V(0) -> Vt, mb(0). No barrier: iter-0 B2 covers it. ----
    {
        s8x v0a = *reinterpret_cast<const s8x*>(vbase + (size_t)(2 * vp) * rs + vs * 16);
        s8x v0b = *reinterpret_cast<const s8x*>(vbase + (size_t)(2 * vp) * rs + vs * 16 + 8);
        s8x v1a = *reinterpret_cast<const s8x*>(vbase + (size_t)(2 * vp + 1) * rs + vs * 16);
        s8x v1b = *reinterpret_cast<const s8x*>(vbase + (size_t)(2 * vp + 1) * rs + vs * 16 + 8);
        if (t < 64) mbuf[0][t] = mask[b * T_SEQ + t] ? 0.f : -__builtin_inff();
        #pragma unroll
        for (int j = 0; j < 8; j++) {
            int r0 = vs * 16 + j, r1 = vs * 16 + 8 + j;
            unsigned w0 = (u16)v0a[j] | ((unsigned)(u16)v1a[j] << 16);
            unsigned w1 = (u16)v0b[j] | ((unsigned)(u16)v1b[j] << 16);
            *reinterpret_cast<unsigned*>(&Vt[r0 * 64 + (((vp >> 2) ^ (r0 & 7)) << 3) + (vp & 3) * 2]) = w0;
            *reinterpret_cast<unsigned*>(&Vt[r1 * 64 + (((vp >> 2) ^ (r1 & 7)) << 3) + (vp & 3) * 2]) = w1;
        }
    }

    for (int tt = 0; tt < T_SEQ / 64; tt++) {
        int kv0 = tt * 64;
        int cur = tt & 1, nxt = cur ^ 1;
        int kvn = kv0 + 64; if (kvn >= T_SEQ) kvn = 0;   // wrap: harmless dummy prefetch

        // --- issue V(t+1) loads EARLY; regs live across both barriers ---
        s8x v0a = *reinterpret_cast<const s8x*>(vbase + (size_t)(kvn + 2 * vp) * rs + vs * 16);
        s8x v0b = *reinterpret_cast<const s8x*>(vbase + (size_t)(kvn + 2 * vp) * rs + vs * 16 + 8);
        s8x v1a = *reinterpret_cast<const s8x*>(vbase + (size_t)(kvn + 2 * vp + 1) * rs + vs * 16);
        s8x v1b = *reinterpret_cast<const s8x*>(vbase + (size_t)(kvn + 2 * vp + 1) * rs + vs * 16 + 8);

        // --- QK^T: S[q][k] (pre-scaled exp2 domain), K frags from global ---
        f4x sf[2][4] = {};
        #pragma unroll
        for (int t4 = 0; t4 < 4; t4++) {
            s8x kf[4];
            #pragma unroll
            for (int kk = 0; kk < 4; kk++)
                kf[kk] = *reinterpret_cast<const s8x*>(
                    kbase + (size_t)(kv0 + t4 * 16 + l15) * rs + kk * 32 + l4 * 8);
            #pragma unroll
            for (int ms = 0; ms < 2; ms++)
                #pragma unroll
                for (int kk = 0; kk < 4; kk++)
                    sf[ms][t4] = __builtin_amdgcn_mfma_f32_16x16x32_bf16(qf[ms][kk], kf[kk], sf[ms][t4], 0, 0, 0);
        }

        __syncthreads();   // B2: prev-tile Vt/mbuf writes visible

        // mask bias add (col = t4*16 + l15)
        float mbv[4];
        #pragma unroll
        for (int t4 = 0; t4 < 4; t4++) mbv[t4] = mbuf[cur][t4 * 16 + l15];
        #pragma unroll
        for (int ms = 0; ms < 2; ms++)
            #pragma unroll
            for (int t4 = 0; t4 < 4; t4++)
                sf[ms][t4] += mbv[t4];

        // --- online softmax (exp2 domain; DPP row-max; defer-max T13) ---
        #pragma unroll
        for (int ms = 0; ms < 2; ms++) {
            float mx[4];
            #pragma unroll
            for (int r = 0; r < 4; r++) {
                float a0 = fmaxf(fmaxf(sf[ms][0][r], sf[ms][1][r]),
                                 fmaxf(sf[ms][2][r], sf[ms][3][r]));
                mx[r] = rowmax16(a0);
            }
            bool grow = false;
            #pragma unroll
            for (int r = 0; r < 4; r++) grow |= (mx[r] > mrun[ms][r] + 8.f);
            if (__any(grow)) {
                f4x fv;
                #pragma unroll
                for (int r = 0; r < 4; r++) {
                    float mn = fmaxf(mrun[ms][r], mx[r]);
                    fv[r] = exp2f(mrun[ms][r] - mn);
                    mrun[ms][r] = mn;
                    lrun[ms][r] *= fv[r];
                }
                #pragma unroll
                for (int dt = 0; dt < 8; dt++) acc[ms][dt] *= fv;
            }
            #pragma unroll
            for (int t4 = 0; t4 < 4; t4++) {
                int pslot = (t4 << 1) + (l15 >> 3);
                #pragma unroll
                for (int r = 0; r < 4; r++) {
                    float p = exp2f(sf[ms][t4][r] - mrun[ms][r]);
                    lrun[ms][r] += p;
                    int prow = ms * 16 + l4 * 4 + r;
                    Pw[prow * 64 + ((pslot ^ (prow & 7)) << 3) + (l15 & 7)] = f2bf(p);
                }
            }
        }
        asm volatile("" ::: "memory"); // order same-wave P writes vs reads

        // --- PV: acc += P * V(t), swizzled reads (conflict-free) ---
        s8x pa[2][2];
        #pragma unroll
        for (int ms = 0; ms < 2; ms++)
            #pragma unroll
            for (int ks = 0; ks < 2; ks++) {
                int prow = ms * 16 + l15;
                pa[ms][ks] = *reinterpret_cast<const s8x*>(
                    Pw + prow * 64 + ((((ks << 2) + l4) ^ (prow & 7)) << 3));
            }
        #pragma unroll
        for (int dt = 0; dt < 8; dt++) {
            int vrow = dt * 16 + l15;
            s8x vbf[2];
            #pragma unroll
            for (int ks = 0; ks < 2; ks++)
                vbf[ks] = *reinterpret_cast<const s8x*>(
                    &Vt[vrow * 64 + ((((ks << 2) + l4) ^ (vrow & 7)) << 3)]);
            #pragma unroll
            for (int ms = 0; ms < 2; ms++)
                #pragma unroll
                for (int ks = 0; ks < 2; ks++)
                    acc[ms][dt] = __builtin_amdgcn_mfma_f32_16x16x32_bf16(pa[ms][ks], vbf[ks], acc[ms][dt], 0, 0, 0);
        }

        __syncthreads();   // B1: all waves done reading Vt

        // --- V(t+1) -> Vt (overwrite), mb(t+1) ---
        if (t < 64) mbuf[nxt][t] = mask[b * T_SEQ + kvn + t] ? 0.f : -__builtin_inff();
        #pragma unroll
        for (int j = 0; j < 8; j++) {
            int r0 = vs * 16 + j, r1 = vs * 16 + 8 + j;
            unsigned w0 = (u16)v0a[j] | ((unsigned)(u16)v1a[j] << 16);
            unsigned w1 = (u16)v0b[j] | ((unsigned)(u16)v1b[j] << 16);
            *reinterpret_cast<unsigned*>(&Vt[r0 * 64 + (((vp >> 2) ^ (r0 & 7)) << 3) + (vp & 3) * 2]) = w0;
            *reinterpret_cast<unsigned*>(&Vt[r1 * 64 + (((vp >> 2) ^ (r1 & 7)) << 3) + (vp & 3) * 2]) = w1;
        }
        // next iter's B2 orders these writes before their readers
    }

    // --- epilogue: normalize and store bf16 attended ---
    #pragma unroll
    for (int ms = 0; ms < 2; ms++) {
        f4x inv;
        #pragma unroll
        for (int r = 0; r < 4; r++) {
            float s = lrun[ms][r];
            #pragma unroll
            for (int sh = 1; sh <= 8; sh <<= 1) s += __shfl_xor(s, sh);
            inv[r] = 1.f / s;
        }
        #pragma unroll
        for (int dt = 0; dt < 8; dt++) {
            f4x o = acc[ms][dt] * inv;
            #pragma unroll
            for (int r = 0; r < 4; r++) {
                int row = qb * 128 + wid * 32 + ms * 16 + l4 * 4 + r;
                int col = h * HD + dt * 16 + l15;
                att[(size_t)(b * T_SEQ + row) * D_MODEL + col] = f2bf(o[r]);
            }
        }
    }
}

// ---------------------------------------------------------------------------
// Launcher
// ---------------------------------------------------------------------------
extern "C" void kernel_launch(void* const* d_in, const int* in_sizes, int n_in,
                              void* d_out, int out_size, void* d_ws, size_t ws_size,
                              hipStream_t stream) {
    (void)in_sizes; (void)n_in; (void)out_size; (void)ws_size;

    const float* x    = (const float*)d_in[0];
    const int*   mask = (const int*)d_in[1];
    const float* Wq   = (const float*)d_in[2];
    const float* bq   = (const float*)d_in[3];
    const float* Wk   = (const float*)d_in[4];
    const float* bk   = (const float*)d_in[5];
    const float* Wv   = (const float*)d_in[6];
    const float* bv   = (const float*)d_in[7];
    const float* Wo   = (const float*)d_in[8];
    const float* bo   = (const float*)d_in[9];
    float* out = (float*)d_out;

    char* ws = (char*)d_ws;
    // workspace layout (bytes):
    u16*   xb   = (u16*)(ws);               // x bf16        8192x2048 : 33,554,432
    u16*   wqkv = (u16*)(ws + 33554432);    // Wq|Wk|Wv bf16 6144x2048 : 25,165,824
    u16*   wo   = (u16*)(ws + 58720256);    // Wo bf16       2048x2048 :  8,388,608
    float* bqkv = (float*)(ws + 67108864);  // bq|bk|bv fp32 6144      :     24,576
    u16*   qkvb = (u16*)(ws + 67133440);    // qkv bf16      8192x6144 :100,663,296
    u16*   attb = (u16*)(ws + 167796736);   // attended bf16 8192x2048 : 33,554,432
                                            // total: 201,351,168 B

    cvt_f32_bf16<<<2048, 256, 0, stream>>>(x,  xb,               16777216 / 8);
    cvt_f32_bf16<<<1024, 256, 0, stream>>>(Wq, wqkv,              4194304 / 8);
    cvt_f32_bf16<<<1024, 256, 0, stream>>>(Wk, wqkv + 4194304,    4194304 / 8);
    cvt_f32_bf16<<<1024, 256, 0, stream>>>(Wv, wqkv + 8388608,    4194304 / 8);
    cvt_f32_bf16<<<1024, 256, 0, stream>>>(Wo, wo,                4194304 / 8);
    hipMemcpyAsync(bqkv,        bq, 2048 * 4, hipMemcpyDeviceToDevice, stream);
    hipMemcpyAsync(bqkv + 2048, bk, 2048 * 4, hipMemcpyDeviceToDevice, stream);
    hipMemcpyAsync(bqkv + 4096, bv, 2048 * 4, hipMemcpyDeviceToDevice, stream);

    const float cs = 0.08838834764831845f * 1.4426950408889634f; // 1/sqrt(128)*log2(e)

    // QKV projection: C[8192][6144] = x * [Wq|Wk|Wv]^T + b   (Q cols pre-scaled by cs)
    gemm_bt<true><<<64 * 48, 256, 0, stream>>>(xb, wqkv, bqkv, qkvb, M_ROWS, N_QKV, D_MODEL, 48, cs, D_MODEL);
    // fused flash attention -> attended bf16 [8192][2048]
    attn<<<1024, 256, 0, stream>>>(qkvb, mask, attb);
    // output projection: out fp32 = attended * Wo^T + bo
    gemm_bt<false><<<64 * 16, 256, 0, stream>>>(attb, wo, bo, out, M_ROWS, D_MODEL, D_MODEL, 16, 1.0f, 0);
}

// Round 4
// 901.482 us; speedup vs baseline: 1.8837x; 1.8837x over previous
//
#include <hip/hip_runtime.h>
#include <cstdint>
#include <cstddef>

// Problem constants (fixed shapes from the reference)
#define D_MODEL 2048
#define T_SEQ   2048
#define N_BATCH 4
#define N_HEAD  16
#define HD      128
#define M_ROWS  (N_BATCH * T_SEQ)   // 8192
#define N_QKV   (3 * D_MODEL)       // 6144

typedef short          s8x  __attribute__((ext_vector_type(8)));   // 8 x bf16 (4 VGPRs)
typedef float          f4x  __attribute__((ext_vector_type(4)));
typedef float          f4v  __attribute__((ext_vector_type(4)));
typedef unsigned short u16;
typedef u16            u16x8 __attribute__((ext_vector_type(8)));

// fp32 -> bf16, round-to-nearest-even
__device__ __forceinline__ u16 f2bf(float f) {
    union { float f; unsigned u; } v; v.f = f;
    unsigned r = (v.u + 0x7FFFu + ((v.u >> 16) & 1u)) >> 16;
    return (u16)r;
}

// async global->LDS, 16B per lane (GEMM staging only)
__device__ __forceinline__ void glds16(const void* g, void* l) {
    __builtin_amdgcn_global_load_lds(
        (const __attribute__((address_space(1))) void*)g,
        (__attribute__((address_space(3))) void*)l, 16, 0, 0);
}

// DPP row_ror butterfly step: lane i of each 16-lane row reads lane (i+N)&15
template<int CTRL>
__device__ __forceinline__ float dppror(float v) {
    int i = __builtin_bit_cast(int, v);
    int r = __builtin_amdgcn_update_dpp(i, i, CTRL, 0xf, 0xf, true);
    return __builtin_bit_cast(float, r);
}
// max over the 16 lanes of a DPP row, result broadcast to all 16
__device__ __forceinline__ float rowmax16(float v) {
    v = fmaxf(v, dppror<0x128>(v));   // row_ror:8
    v = fmaxf(v, dppror<0x124>(v));   // row_ror:4
    v = fmaxf(v, dppror<0x122>(v));   // row_ror:2
    v = fmaxf(v, dppror<0x121>(v));   // row_ror:1
    return v;
}

// ---------------------------------------------------------------------------
// fp32 -> bf16 bulk convert (8 elements / thread / iter)
// ---------------------------------------------------------------------------
__global__ void cvt_f32_bf16(const float* __restrict__ in, u16* __restrict__ out, int n8) {
    int i = blockIdx.x * blockDim.x + threadIdx.x;
    int stride = gridDim.x * blockDim.x;
    for (; i < n8; i += stride) {
        f4v a = reinterpret_cast<const f4v*>(in)[2 * i];
        f4v b = reinterpret_cast<const f4v*>(in)[2 * i + 1];
        u16x8 o;
        o[0] = f2bf(a[0]); o[1] = f2bf(a[1]); o[2] = f2bf(a[2]); o[3] = f2bf(a[3]);
        o[4] = f2bf(b[0]); o[5] = f2bf(b[1]); o[6] = f2bf(b[2]); o[7] = f2bf(b[3]);
        reinterpret_cast<u16x8*>(out)[i] = o;
    }
}

// ---------------------------------------------------------------------------
// C[m][n] = (sum_k A[m][k]*B[n][k] + bias[n]) * (col<qcols ? qscale : 1)
// (B^T layout, m97 structure) 128x128 tile, BK=32, 4 waves, 4x4 16x16 frags.
// ---------------------------------------------------------------------------
template<bool OUT_BF16>
__global__ __launch_bounds__(256)
void gemm_bt(const u16* __restrict__ A, const u16* __restrict__ B,
             const float* __restrict__ bias, void* __restrict__ C,
             int M, int N, int K, int nbn, float qscale, int qcols) {
    __shared__ u16 As[128 * 32];
    __shared__ u16 Bs[128 * 32];

    int nwg = gridDim.x;
    int wg  = blockIdx.x;
    int qx  = nwg >> 3;                 // nwg % 8 == 0 by construction
    wg = (wg & 7) * qx + (wg >> 3);     // XCD-aware swizzle
    int bm = wg / nbn, bn = wg % nbn;

    int t   = threadIdx.x;
    int wid = t >> 6;
    int l15 = t & 15, l4 = (t >> 4) & 3;
    int wr  = wid >> 1, wc = wid & 1;

    f4x acc[4][4] = {};

    const u16* ga = A + (size_t)(bm * 128 + (t >> 2)) * K + (t & 3) * 8;
    const u16* gb = B + (size_t)(bn * 128 + (t >> 2)) * K + (t & 3) * 8;
    char* lA = (char*)As + wid * 1024;
    char* lB = (char*)Bs + wid * 1024;

    for (int k0 = 0; k0 < K; k0 += 32) {
        glds16(ga,              lA);
        glds16(ga + 64 * (size_t)K, lA + 4096);
        glds16(gb,              lB);
        glds16(gb + 64 * (size_t)K, lB + 4096);
        ga += 32; gb += 32;
        __syncthreads();

        s8x af[4], bfr[4];
        #pragma unroll
        for (int m = 0; m < 4; m++) {
            af[m]  = *reinterpret_cast<const s8x*>(As + (wr * 64 + m * 16 + l15) * 32 + l4 * 8);
            bfr[m] = *reinterpret_cast<const s8x*>(Bs + (wc * 64 + m * 16 + l15) * 32 + l4 * 8);
        }
        #pragma unroll
        for (int m = 0; m < 4; m++)
            #pragma unroll
            for (int n = 0; n < 4; n++)
                acc[m][n] = __builtin_amdgcn_mfma_f32_16x16x32_bf16(af[m], bfr[n], acc[m][n], 0, 0, 0);
        __syncthreads();
    }

    int row0 = bm * 128 + wr * 64;
    int col0 = bn * 128 + wc * 64;
    #pragma unroll
    for (int n = 0; n < 4; n++) {
        int col = col0 + n * 16 + l15;
        float bv = bias[col];
        float sc = (col < qcols) ? qscale : 1.0f;
        #pragma unroll
        for (int m = 0; m < 4; m++) {
            #pragma unroll
            for (int r = 0; r < 4; r++) {
                int row = row0 + m * 16 + l4 * 4 + r;
                float v = (acc[m][n][r] + bv) * sc;
                if (OUT_BF16) ((u16*)C)[(size_t)row * N + col]   = f2bf(v);
                else          ((float*)C)[(size_t)row * N + col] = v;
            }
        }
    }
}

// ---------------------------------------------------------------------------
// Flash attention v4 = v3 structure with the spill-inducing launch bound
// reverted to (256,2) (r3 post-mortem: (256,4) forced VGPR 108->64 and
// 4.2 GB/dispatch of scratch traffic).
// Grid = 64 (b*h) x 16 q-blocks. 256 threads = 4 waves.
//  - K fragments read DIRECTLY from global (L2-resident)
//  - V issued-early per tile, reg-held across both barriers, SINGLE-buffered
//    Vt with 16B-slot XOR swizzle (slot ^ row&7): LDS 33 KB -> 4 blocks/CU
//  - Pl per-wave, same XOR swizzle (verified: 0 bank-conflict cycles in r3)
//  - defer-max (T13, THR=8)
//  - barrier schedule: QK -> B2 -> softmax+P -> PV -> B1 -> V-transpose
// ---------------------------------------------------------------------------
__global__ __launch_bounds__(256, 2)
void attn(const u16* __restrict__ qkv, const int* __restrict__ mask,
          u16* __restrict__ att) {
    __shared__ u16  Vt[128 * 64];      // 16 KB, transposed V, XOR-swizzled slots
    __shared__ u16  Pl[4][32 * 64];    // 16 KB, per-wave P tile, XOR-swizzled
    __shared__ float mbuf[2][64];      // mask bias, double-buffered (512 B)

    int wg = blockIdx.x;               // 1024
    int q8 = gridDim.x >> 3;
    wg = (wg & 7) * q8 + (wg >> 3);    // XCD swizzle
    int bh = wg >> 4;
    int qb = wg & 15;
    int b  = bh >> 4, h = bh & 15;

    int t = threadIdx.x, wid = t >> 6;
    int lane = t & 63, l15 = lane & 15, l4 = lane >> 4;

    const size_t rs = N_QKV;           // 6144 qkv row stride
    const u16* qbase = qkv + (size_t)(b * T_SEQ) * rs;
    const u16* kbase = qbase + D_MODEL + h * HD;
    const u16* vbase = qbase + 2 * D_MODEL + h * HD;

    // Q fragments in registers (pre-scaled by 1/sqrt(d)*log2e in GEMM1)
    s8x qf[2][4];
    #pragma unroll
    for (int ms = 0; ms < 2; ms++)
        #pragma unroll
        for (int kk = 0; kk < 4; kk++) {
            int row = qb * 128 + wid * 32 + ms * 16 + l15;
            qf[ms][kk] = *reinterpret_cast<const s8x*>(
                qbase + (size_t)row * rs + h * HD + kk * 32 + l4 * 8);
        }

    f4x acc[2][8] = {};
    float mrun[2][4], lrun[2][4];
    #pragma unroll
    for (int ms = 0; ms < 2; ms++)
        #pragma unroll
        for (int r = 0; r < 4; r++) { mrun[ms][r] = -__builtin_inff(); lrun[ms][r] = 0.f; }

    int vp = t & 31;    // key pair index (k = 2vp, 2vp+1)
    int vs = t >> 5;    // d slot (d0 = vs*16)
    u16* Pw = Pl[wid];

    // ---- prologue: V(0) -> Vt, mb(0). No barrier: iter-0 B2 covers it. ----
    {
        s8x v0a = *reinterpret_cast<const s8x*>(vbase + (size_t)(2 * vp) * rs + vs * 16);
        s8x v0b = *reinterpret_cast<const s8x*>(vbase + (size_t)(2 * vp) * rs + vs * 16 + 8);
        s8x v1a = *reinterpret_cast<const s8x*>(vbase + (size_t)(2 * vp + 1) * rs + vs * 16);
        s8x v1b = *reinterpret_cast<const s8x*>(vbase + (size_t)(2 * vp + 1) * rs + vs * 16 + 8);
        if (t < 64) mbuf[0][t] = mask[b * T_SEQ + t] ? 0.f : -__builtin_inff();
        #pragma unroll
        for (int j = 0; j < 8; j++) {
            int r0 = vs * 16 + j, r1 = vs * 16 + 8 + j;
            unsigned w0 = (u16)v0a[j] | ((unsigned)(u16)v1a[j] << 16);
            unsigned w1 = (u16)v0b[j] | ((unsigned)(u16)v1b[j] << 16);
            *reinterpret_cast<unsigned*>(&Vt[r0 * 64 + (((vp >> 2) ^ (r0 & 7)) << 3) + (vp & 3) * 2]) = w0;
            *reinterpret_cast<unsigned*>(&Vt[r1 * 64 + (((vp >> 2) ^ (r1 & 7)) << 3) + (vp & 3) * 2]) = w1;
        }
    }

    for (int tt = 0; tt < T_SEQ / 64; tt++) {
        int kv0 = tt * 64;
        int cur = tt & 1, nxt = cur ^ 1;
        int kvn = kv0 + 64; if (kvn >= T_SEQ) kvn = 0;   // wrap: harmless dummy prefetch

        // --- issue V(t+1) loads EARLY; regs live across both barriers ---
        s8x v0a = *reinterpret_cast<const s8x*>(vbase + (size_t)(kvn + 2 * vp) * rs + vs * 16);
        s8x v0b = *reinterpret_cast<const s8x*>(vbase + (size_t)(kvn + 2 * vp) * rs + vs * 16 + 8);
        s8x v1a = *reinterpret_cast<const s8x*>(vbase + (size_t)(kvn + 2 * vp + 1) * rs + vs * 16);
        s8x v1b = *reinterpret_cast<const s8x*>(vbase + (size_t)(kvn + 2 * vp + 1) * rs + vs * 16 + 8);

        // --- QK^T: S[q][k] (pre-scaled exp2 domain), K frags from global ---
        f4x sf[2][4] = {};
        #pragma unroll
        for (int t4 = 0; t4 < 4; t4++) {
            s8x kf[4];
            #pragma unroll
            for (int kk = 0; kk < 4; kk++)
                kf[kk] = *reinterpret_cast<const s8x*>(
                    kbase + (size_t)(kv0 + t4 * 16 + l15) * rs + kk * 32 + l4 * 8);
            #pragma unroll
            for (int ms = 0; ms < 2; ms++)
                #pragma unroll
                for (int kk = 0; kk < 4; kk++)
                    sf[ms][t4] = __builtin_amdgcn_mfma_f32_16x16x32_bf16(qf[ms][kk], kf[kk], sf[ms][t4], 0, 0, 0);
        }

        __syncthreads();   // B2: prev-tile Vt/mbuf writes visible

        // mask bias add (col = t4*16 + l15)
        float mbv[4];
        #pragma unroll
        for (int t4 = 0; t4 < 4; t4++) mbv[t4] = mbuf[cur][t4 * 16 + l15];
        #pragma unroll
        for (int ms = 0; ms < 2; ms++)
            #pragma unroll
            for (int t4 = 0; t4 < 4; t4++)
                sf[ms][t4] += mbv[t4];

        // --- online softmax (exp2 domain; DPP row-max; defer-max T13) ---
        #pragma unroll
        for (int ms = 0; ms < 2; ms++) {
            float mx[4];
            #pragma unroll
            for (int r = 0; r < 4; r++) {
                float a0 = fmaxf(fmaxf(sf[ms][0][r], sf[ms][1][r]),
                                 fmaxf(sf[ms][2][r], sf[ms][3][r]));
                mx[r] = rowmax16(a0);
            }
            bool grow = false;
            #pragma unroll
            for (int r = 0; r < 4; r++) grow |= (mx[r] > mrun[ms][r] + 8.f);
            if (__any(grow)) {
                f4x fv;
                #pragma unroll
                for (int r = 0; r < 4; r++) {
                    float mn = fmaxf(mrun[ms][r], mx[r]);
                    fv[r] = exp2f(mrun[ms][r] - mn);
                    mrun[ms][r] = mn;
                    lrun[ms][r] *= fv[r];
                }
                #pragma unroll
                for (int dt = 0; dt < 8; dt++) acc[ms][dt] *= fv;
            }
            #pragma unroll
            for (int t4 = 0; t4 < 4; t4++) {
                int pslot = (t4 << 1) + (l15 >> 3);
                #pragma unroll
                for (int r = 0; r < 4; r++) {
                    float p = exp2f(sf[ms][t4][r] - mrun[ms][r]);
                    lrun[ms][r] += p;
                    int prow = ms * 16 + l4 * 4 + r;
                    Pw[prow * 64 + ((pslot ^ (prow & 7)) << 3) + (l15 & 7)] = f2bf(p);
                }
            }
        }
        asm volatile("" ::: "memory"); // order same-wave P writes vs reads

        // --- PV: acc += P * V(t), swizzled reads (conflict-free) ---
        s8x pa[2][2];
        #pragma unroll
        for (int ms = 0; ms < 2; ms++)
            #pragma unroll
            for (int ks = 0; ks < 2; ks++) {
                int prow = ms * 16 + l15;
                pa[ms][ks] = *reinterpret_cast<const s8x*>(
                    Pw + prow * 64 + ((((ks << 2) + l4) ^ (prow & 7)) << 3));
            }
        #pragma unroll
        for (int dt = 0; dt < 8; dt++) {
            int vrow = dt * 16 + l15;
            s8x vbf[2];
            #pragma unroll
            for (int ks = 0; ks < 2; ks++)
                vbf[ks] = *reinterpret_cast<const s8x*>(
                    &Vt[vrow * 64 + ((((ks << 2) + l4) ^ (vrow & 7)) << 3)]);
            #pragma unroll
            for (int ms = 0; ms < 2; ms++)
                #pragma unroll
                for (int ks = 0; ks < 2; ks++)
                    acc[ms][dt] = __builtin_amdgcn_mfma_f32_16x16x32_bf16(pa[ms][ks], vbf[ks], acc[ms][dt], 0, 0, 0);
        }

        __syncthreads();   // B1: all waves done reading Vt

        // --- V(t+1) -> Vt (overwrite), mb(t+1) ---
        if (t < 64) mbuf[nxt][t] = mask[b * T_SEQ + kvn + t] ? 0.f : -__builtin_inff();
        #pragma unroll
        for (int j = 0; j < 8; j++) {
            int r0 = vs * 16 + j, r1 = vs * 16 + 8 + j;
            unsigned w0 = (u16)v0a[j] | ((unsigned)(u16)v1a[j] << 16);
            unsigned w1 = (u16)v0b[j] | ((unsigned)(u16)v1b[j] << 16);
            *reinterpret_cast<unsigned*>(&Vt[r0 * 64 + (((vp >> 2) ^ (r0 & 7)) << 3) + (vp & 3) * 2]) = w0;
            *reinterpret_cast<unsigned*>(&Vt[r1 * 64 + (((vp >> 2) ^ (r1 & 7)) << 3) + (vp & 3) * 2]) = w1;
        }
        // next iter's B2 orders these writes before their readers
    }

    // --- epilogue: normalize and store bf16 attended ---
    #pragma unroll
    for (int ms = 0; ms < 2; ms++) {
        f4x inv;
        #pragma unroll
        for (int r = 0; r < 4; r++) {
            float s = lrun[ms][r];
            #pragma unroll
            for (int sh = 1; sh <= 8; sh <<= 1) s += __shfl_xor(s, sh);
            inv[r] = 1.f / s;
        }
        #pragma unroll
        for (int dt = 0; dt < 8; dt++) {
            f4x o = acc[ms][dt] * inv;
            #pragma unroll
            for (int r = 0; r < 4; r++) {
                int row = qb * 128 + wid * 32 + ms * 16 + l4 * 4 + r;
                int col = h * HD + dt * 16 + l15;
                att[(size_t)(b * T_SEQ + row) * D_MODEL + col] = f2bf(o[r]);
            }
        }
    }
}

// ---------------------------------------------------------------------------
// Launcher
// ---------------------------------------------------------------------------
extern "C" void kernel_launch(void* const* d_in, const int* in_sizes, int n_in,
                              void* d_out, int out_size, void* d_ws, size_t ws_size,
                              hipStream_t stream) {
    (void)in_sizes; (void)n_in; (void)out_size; (void)ws_size;

    const float* x    = (const float*)d_in[0];
    const int*   mask = (const int*)d_in[1];
    const float* Wq   = (const float*)d_in[2];
    const float* bq   = (const float*)d_in[3];
    const float* Wk   = (const float*)d_in[4];
    const float* bk   = (const float*)d_in[5];
    const float* Wv   = (const float*)d_in[6];
    const float* bv   = (const float*)d_in[7];
    const float* Wo   = (const float*)d_in[8];
    const float* bo   = (const float*)d_in[9];
    float* out = (float*)d_out;

    char* ws = (char*)d_ws;
    // workspace layout (bytes):
    u16*   xb   = (u16*)(ws);               // x bf16        8192x2048 : 33,554,432
    u16*   wqkv = (u16*)(ws + 33554432);    // Wq|Wk|Wv bf16 6144x2048 : 25,165,824
    u16*   wo   = (u16*)(ws + 58720256);    // Wo bf16       2048x2048 :  8,388,608
    float* bqkv = (float*)(ws + 67108864);  // bq|bk|bv fp32 6144      :     24,576
    u16*   qkvb = (u16*)(ws + 67133440);    // qkv bf16      8192x6144 :100,663,296
    u16*   attb = (u16*)(ws + 167796736);   // attended bf16 8192x2048 : 33,554,432
                                            // total: 201,351,168 B

    cvt_f32_bf16<<<2048, 256, 0, stream>>>(x,  xb,               16777216 / 8);
    cvt_f32_bf16<<<1024, 256, 0, stream>>>(Wq, wqkv,              4194304 / 8);
    cvt_f32_bf16<<<1024, 256, 0, stream>>>(Wk, wqkv + 4194304,    4194304 / 8);
    cvt_f32_bf16<<<1024, 256, 0, stream>>>(Wv, wqkv + 8388608,    4194304 / 8);
    cvt_f32_bf16<<<1024, 256, 0, stream>>>(Wo, wo,                4194304 / 8);
    hipMemcpyAsync(bqkv,        bq, 2048 * 4, hipMemcpyDeviceToDevice, stream);
    hipMemcpyAsync(bqkv + 2048, bk, 2048 * 4, hipMemcpyDeviceToDevice, stream);
    hipMemcpyAsync(bqkv + 4096, bv, 2048 * 4, hipMemcpyDeviceToDevice, stream);

    const float cs = 0.08838834764831845f * 1.4426950408889634f; // 1/sqrt(128)*log2(e)

    // QKV projection: C[8192][6144] = x * [Wq|Wk|Wv]^T + b   (Q cols pre-scaled by cs)
    gemm_bt<true><<<64 * 48, 256, 0, stream>>>(xb, wqkv, bqkv, qkvb, M_ROWS, N_QKV, D_MODEL, 48, cs, D_MODEL);
    // fused flash attention -> attended bf16 [8192][2048]
    attn<<<1024, 256, 0, stream>>>(qkvb, mask, attb);
    // output projection: out fp32 = attended * Wo^T + bo
    gemm_bt<false><<<64 * 16, 256, 0, stream>>>(attb, wo, bo, out, M_ROWS, D_MODEL, D_MODEL, 16, 1.0f, 0);
}

// Round 5
// 853.806 us; speedup vs baseline: 1.9889x; 1.0558x over previous
//
#include <hip/hip_runtime.h>
#include <cstdint>
#include <cstddef>

// Problem constants (fixed shapes from the reference)
#define D_MODEL 2048
#define T_SEQ   2048
#define N_BATCH 4
#define N_HEAD  16
#define HD      128
#define M_ROWS  (N_BATCH * T_SEQ)   // 8192
#define N_QKV   (3 * D_MODEL)       // 6144

typedef short          s8x   __attribute__((ext_vector_type(8)));   // 8 x bf16
typedef float          f4x   __attribute__((ext_vector_type(4)));
typedef float          f16x  __attribute__((ext_vector_type(16)));
typedef float          f4v   __attribute__((ext_vector_type(4)));
typedef unsigned short u16;
typedef u16            u16x8 __attribute__((ext_vector_type(8)));

// fp32 -> bf16, round-to-nearest-even (epilogue-only use)
__device__ __forceinline__ u16 f2bf(float f) {
    union { float f; unsigned u; } v; v.f = f;
    unsigned r = (v.u + 0x7FFFu + ((v.u >> 16) & 1u)) >> 16;
    return (u16)r;
}

// packed f32x2 -> bf16x2 (RNE), single HW instr
__device__ __forceinline__ unsigned pkbf(float lo, float hi) {
    unsigned r;
    asm("v_cvt_pk_bf16_f32 %0, %1, %2" : "=v"(r) : "v"(lo), "v"(hi));
    return r;
}
// v_permlane32_swap_b32: a' = [a.lo | b.lo], b' = [a.hi | b.hi]
__device__ __forceinline__ void pl32swap(unsigned& a, unsigned& b) {
    asm volatile("v_permlane32_swap_b32 %0, %1" : "+v"(a), "+v"(b));
}

// async global->LDS, 16B per lane (GEMM staging only)
__device__ __forceinline__ void glds16(const void* g, void* l) {
    __builtin_amdgcn_global_load_lds(
        (const __attribute__((address_space(1))) void*)g,
        (__attribute__((address_space(3))) void*)l, 16, 0, 0);
}

// ---------------------------------------------------------------------------
// fp32 -> bf16 bulk convert (8 elements / thread / iter)
// ---------------------------------------------------------------------------
__global__ void cvt_f32_bf16(const float* __restrict__ in, u16* __restrict__ out, int n8) {
    int i = blockIdx.x * blockDim.x + threadIdx.x;
    int stride = gridDim.x * blockDim.x;
    for (; i < n8; i += stride) {
        f4v a = reinterpret_cast<const f4v*>(in)[2 * i];
        f4v b = reinterpret_cast<const f4v*>(in)[2 * i + 1];
        u16x8 o;
        o[0] = f2bf(a[0]); o[1] = f2bf(a[1]); o[2] = f2bf(a[2]); o[3] = f2bf(a[3]);
        o[4] = f2bf(b[0]); o[5] = f2bf(b[1]); o[6] = f2bf(b[2]); o[7] = f2bf(b[3]);
        reinterpret_cast<u16x8*>(out)[i] = o;
    }
}

// ---------------------------------------------------------------------------
// C[m][n] = (sum_k A[m][k]*B[n][k] + bias[n]) * (col<qcols ? qscale : 1)
// (B^T layout, m97 structure) 128x128 tile, BK=32, 4 waves, 4x4 16x16 frags.
// ---------------------------------------------------------------------------
template<bool OUT_BF16>
__global__ __launch_bounds__(256)
void gemm_bt(const u16* __restrict__ A, const u16* __restrict__ B,
             const float* __restrict__ bias, void* __restrict__ C,
             int M, int N, int K, int nbn, float qscale, int qcols) {
    __shared__ u16 As[128 * 32];
    __shared__ u16 Bs[128 * 32];

    int nwg = gridDim.x;
    int wg  = blockIdx.x;
    int qx  = nwg >> 3;                 // nwg % 8 == 0 by construction
    wg = (wg & 7) * qx + (wg >> 3);     // XCD-aware swizzle
    int bm = wg / nbn, bn = wg % nbn;

    int t   = threadIdx.x;
    int wid = t >> 6;
    int l15 = t & 15, l4 = (t >> 4) & 3;
    int wr  = wid >> 1, wc = wid & 1;

    f4x acc[4][4] = {};

    const u16* ga = A + (size_t)(bm * 128 + (t >> 2)) * K + (t & 3) * 8;
    const u16* gb = B + (size_t)(bn * 128 + (t >> 2)) * K + (t & 3) * 8;
    char* lA = (char*)As + wid * 1024;
    char* lB = (char*)Bs + wid * 1024;

    for (int k0 = 0; k0 < K; k0 += 32) {
        glds16(ga,              lA);
        glds16(ga + 64 * (size_t)K, lA + 4096);
        glds16(gb,              lB);
        glds16(gb + 64 * (size_t)K, lB + 4096);
        ga += 32; gb += 32;
        __syncthreads();

        s8x af[4], bfr[4];
        #pragma unroll
        for (int m = 0; m < 4; m++) {
            af[m]  = *reinterpret_cast<const s8x*>(As + (wr * 64 + m * 16 + l15) * 32 + l4 * 8);
            bfr[m] = *reinterpret_cast<const s8x*>(Bs + (wc * 64 + m * 16 + l15) * 32 + l4 * 8);
        }
        #pragma unroll
        for (int m = 0; m < 4; m++)
            #pragma unroll
            for (int n = 0; n < 4; n++)
                acc[m][n] = __builtin_amdgcn_mfma_f32_16x16x32_bf16(af[m], bfr[n], acc[m][n], 0, 0, 0);
        __syncthreads();
    }

    int row0 = bm * 128 + wr * 64;
    int col0 = bn * 128 + wc * 64;
    #pragma unroll
    for (int n = 0; n < 4; n++) {
        int col = col0 + n * 16 + l15;
        float bv = bias[col];
        float sc = (col < qcols) ? qscale : 1.0f;
        #pragma unroll
        for (int m = 0; m < 4; m++) {
            #pragma unroll
            for (int r = 0; r < 4; r++) {
                int row = row0 + m * 16 + l4 * 4 + r;
                float v = (acc[m][n][r] + bv) * sc;
                if (OUT_BF16) ((u16*)C)[(size_t)row * N + col]   = f2bf(v);
                else          ((float*)C)[(size_t)row * N + col] = v;
            }
        }
    }
}

// ---------------------------------------------------------------------------
// Flash attention v5: swapped-operand 32x32x16 QK^T, fully in-register softmax.
// Grid = 64 (b*h) x 16 q-blocks. 256 threads = 4 waves, 32 q-rows/wave.
//  - QK^T computed as S^T = mfma(K, Q): D col=lane&31=query, row=key
//    -> lane owns 32 P values of ONE query row; row-max/sum are in-lane
//       (+1 shfl_xor(32) to combine the hi/lo key-halves)
//  - P -> bf16 PA frags via v_cvt_pk_bf16_f32 + v_permlane32_swap_b32
//    (derivation: op(P0,P2)->(w0,w2), op(P1,P3)->(w1,w3)); NO P LDS buffer
//  - PV via mfma(P, Vt): B operand rows = d (Vt = V^T, XOR-swizzled slots,
//    verified 0-conflict in r3/r4)
//  - mask as multiply-by-{0,1} with wave-uniform all-ones skip flag
//  - defer-max (T13, THR=8); rescale f redistributed to D-rows via 16 shfl
//    only on the rare __any(grow) event
//  - V issued-early per tile (T14), reg-held across both barriers
//  - barrier schedule: QK -> B2 -> softmax -> PV -> B1 -> V-transpose
// ---------------------------------------------------------------------------
__global__ __launch_bounds__(256, 2)
void attn(const u16* __restrict__ qkv, const int* __restrict__ mask,
          u16* __restrict__ att) {
    __shared__ u16   Vt[128 * 64];     // 16 KB, V^T, XOR-swizzled 16B slots
    __shared__ float mbuf[2][64];      // mask multiplier (1.0 / 0.0)
    __shared__ int   mflag[2];         // 1 = all 64 keys unmasked

    int wg = blockIdx.x;               // 1024
    int q8 = gridDim.x >> 3;
    wg = (wg & 7) * q8 + (wg >> 3);    // XCD swizzle
    int bh = wg >> 4;
    int qb = wg & 15;
    int b  = bh >> 4, h = bh & 15;

    int t = threadIdx.x, wid = t >> 6;
    int lane = t & 63, l31 = lane & 31, hi = lane >> 5;

    const size_t rs = N_QKV;           // 6144 qkv row stride
    const u16* qbase = qkv + (size_t)(b * T_SEQ) * rs;
    const u16* kbase = qbase + D_MODEL + h * HD;
    const u16* vbase = qbase + 2 * D_MODEL + h * HD;

    // Q as B-operand frags (pre-scaled by 1/sqrt(d)*log2e in GEMM1):
    // row q = qrow (lane&31), k = ks*16 + hi*8 + idx
    int qrow = qb * 128 + wid * 32 + l31;
    s8x qf[8];
    #pragma unroll
    for (int ks = 0; ks < 8; ks++)
        qf[ks] = *reinterpret_cast<const s8x*>(
            qbase + (size_t)qrow * rs + h * HD + ks * 16 + hi * 8);

    f16x oacc[4] = {};                 // O[query(reg)][d = db*32 + lane&31]
    float mrun = -__builtin_inff(), lrun = 0.f;

    int vp = t & 31;    // key pair index (k = 2vp, 2vp+1)
    int vs = t >> 5;    // d slot (d0 = vs*16)

    // ---- prologue: V(0) -> Vt, mask(0). iter-0 B2 orders vs readers. ----
    {
        s8x v0a = *reinterpret_cast<const s8x*>(vbase + (size_t)(2 * vp) * rs + vs * 16);
        s8x v0b = *reinterpret_cast<const s8x*>(vbase + (size_t)(2 * vp) * rs + vs * 16 + 8);
        s8x v1a = *reinterpret_cast<const s8x*>(vbase + (size_t)(2 * vp + 1) * rs + vs * 16);
        s8x v1b = *reinterpret_cast<const s8x*>(vbase + (size_t)(2 * vp + 1) * rs + vs * 16 + 8);
        if (wid == 0) {
            int mv = mask[b * T_SEQ + t] != 0;
            mbuf[0][t] = mv ? 1.f : 0.f;
            unsigned long long bl = __ballot(mv);
            if (t == 0) mflag[0] = (bl == ~0ull);
        }
        #pragma unroll
        for (int j = 0; j < 8; j++) {
            int r0 = vs * 16 + j, r1 = vs * 16 + 8 + j;
            unsigned w0 = (u16)v0a[j] | ((unsigned)(u16)v1a[j] << 16);
            unsigned w1 = (u16)v0b[j] | ((unsigned)(u16)v1b[j] << 16);
            *reinterpret_cast<unsigned*>(&Vt[r0 * 64 + (((vp >> 2) ^ (r0 & 7)) << 3) + (vp & 3) * 2]) = w0;
            *reinterpret_cast<unsigned*>(&Vt[r1 * 64 + (((vp >> 2) ^ (r1 & 7)) << 3) + (vp & 3) * 2]) = w1;
        }
    }

    for (int tt = 0; tt < T_SEQ / 64; tt++) {
        int kv0 = tt * 64;
        int cur = tt & 1, nxt = cur ^ 1;
        int kvn = kv0 + 64; if (kvn >= T_SEQ) kvn = 0;   // wrap: dummy prefetch

        // --- issue V(t+1) loads EARLY; regs live across both barriers ---
        s8x v0a = *reinterpret_cast<const s8x*>(vbase + (size_t)(kvn + 2 * vp) * rs + vs * 16);
        s8x v0b = *reinterpret_cast<const s8x*>(vbase + (size_t)(kvn + 2 * vp) * rs + vs * 16 + 8);
        s8x v1a = *reinterpret_cast<const s8x*>(vbase + (size_t)(kvn + 2 * vp + 1) * rs + vs * 16);
        s8x v1b = *reinterpret_cast<const s8x*>(vbase + (size_t)(kvn + 2 * vp + 1) * rs + vs * 16 + 8);

        // --- QK^T swapped: sf[b] = S^T block, keys 32b..32b+31 ---
        f16x sf0 = {}, sf1 = {};
        #pragma unroll
        for (int ks = 0; ks < 8; ks++) {
            s8x k0 = *reinterpret_cast<const s8x*>(
                kbase + (size_t)(kv0 + l31) * rs + ks * 16 + hi * 8);
            s8x k1 = *reinterpret_cast<const s8x*>(
                kbase + (size_t)(kv0 + 32 + l31) * rs + ks * 16 + hi * 8);
            sf0 = __builtin_amdgcn_mfma_f32_32x32x16_bf16(k0, qf[ks], sf0, 0, 0, 0);
            sf1 = __builtin_amdgcn_mfma_f32_32x32x16_bf16(k1, qf[ks], sf1, 0, 0, 0);
        }

        __syncthreads();   // B2: prev-tile Vt/mbuf writes visible

        bool allone = mflag[cur] != 0;

        // --- in-lane row max over this lane's 32 keys, combine hi/lo pair ---
        float a0 = sf0[0], a1 = sf0[1], a2 = sf0[2], a3 = sf0[3];
        #pragma unroll
        for (int r = 4; r < 16; r += 4) {
            a0 = fmaxf(a0, sf0[r]);     a1 = fmaxf(a1, sf0[r + 1]);
            a2 = fmaxf(a2, sf0[r + 2]); a3 = fmaxf(a3, sf0[r + 3]);
        }
        #pragma unroll
        for (int r = 0; r < 16; r += 4) {
            a0 = fmaxf(a0, sf1[r]);     a1 = fmaxf(a1, sf1[r + 1]);
            a2 = fmaxf(a2, sf1[r + 2]); a3 = fmaxf(a3, sf1[r + 3]);
        }
        float mx = fmaxf(fmaxf(a0, a1), fmaxf(a2, a3));
        mx = fmaxf(mx, __shfl_xor(mx, 32));

        // --- defer-max (T13): rescale only when max grows past THR=8 ---
        if (__any(mx > mrun + 8.f)) {
            float mn = fmaxf(mx, mrun);
            float f  = __builtin_amdgcn_exp2f(mrun - mn);
            mrun = mn;
            lrun *= f;
            float fq[16];
            #pragma unroll
            for (int r = 0; r < 16; r++)
                fq[r] = __shfl(f, (r & 3) + 8 * (r >> 2) + 4 * hi);
            #pragma unroll
            for (int db = 0; db < 4; db++)
                #pragma unroll
                for (int r = 0; r < 16; r++)
                    oacc[db][r] *= fq[r];
        }

        // --- P = exp2(S - m) (* mask), partial row-sum in-lane ---
        float p0[16], p1[16];
        #pragma unroll
        for (int r = 0; r < 16; r++) {
            p0[r] = __builtin_amdgcn_exp2f(sf0[r] - mrun);
            p1[r] = __builtin_amdgcn_exp2f(sf1[r] - mrun);
        }
        if (!allone) {
            #pragma unroll
            for (int g = 0; g < 4; g++) {
                f4v m0 = *reinterpret_cast<const f4v*>(&mbuf[cur][8 * g + 4 * hi]);
                f4v m1 = *reinterpret_cast<const f4v*>(&mbuf[cur][32 + 8 * g + 4 * hi]);
                #pragma unroll
                for (int c = 0; c < 4; c++) { p0[4 * g + c] *= m0[c]; p1[4 * g + c] *= m1[c]; }
            }
        }
        {
            float t0 = 0, t1 = 0, t2 = 0, t3 = 0;
            #pragma unroll
            for (int r = 0; r < 16; r += 4) {
                t0 += p0[r];     t1 += p0[r + 1]; t2 += p0[r + 2]; t3 += p0[r + 3];
                t0 += p1[r];     t1 += p1[r + 1]; t2 += p1[r + 2]; t3 += p1[r + 3];
            }
            lrun += (t0 + t1) + (t2 + t3);
        }

        // --- build PA frags: keys s*16 + hi*8 + j for kstep s = 2b + s2 ---
        union { unsigned w[4]; s8x v; } paf[4];
        #pragma unroll
        for (int bb = 0; bb < 2; bb++) {
            float* pp = bb ? p1 : p0;
            #pragma unroll
            for (int s2 = 0; s2 < 2; s2++) {
                unsigned P0 = pkbf(pp[8 * s2 + 0], pp[8 * s2 + 1]);
                unsigned P1 = pkbf(pp[8 * s2 + 2], pp[8 * s2 + 3]);
                unsigned P2 = pkbf(pp[8 * s2 + 4], pp[8 * s2 + 5]);
                unsigned P3 = pkbf(pp[8 * s2 + 6], pp[8 * s2 + 7]);
                pl32swap(P0, P2);      // -> (w0, w2)
                pl32swap(P1, P3);      // -> (w1, w3)
                int s = 2 * bb + s2;
                paf[s].w[0] = P0; paf[s].w[1] = P1;
                paf[s].w[2] = P2; paf[s].w[3] = P3;
            }
        }

        // --- PV: O += P * V^T, Vt swizzled reads ---
        #pragma unroll
        for (int db = 0; db < 4; db++) {
            int vrow = db * 32 + l31;
            #pragma unroll
            for (int s = 0; s < 4; s++) {
                int slot = ((s << 1) + hi) ^ (vrow & 7);
                s8x vb = *reinterpret_cast<const s8x*>(&Vt[vrow * 64 + slot * 8]);
                oacc[db] = __builtin_amdgcn_mfma_f32_32x32x16_bf16(paf[s].v, vb, oacc[db], 0, 0, 0);
            }
        }

        __syncthreads();   // B1: all waves done reading Vt

        // --- V(t+1) -> Vt (overwrite), mask(t+1) ---
        if (wid == 0) {
            int mv = mask[b * T_SEQ + kvn + t] != 0;
            mbuf[nxt][t] = mv ? 1.f : 0.f;
            unsigned long long bl = __ballot(mv);
            if (t == 0) mflag[nxt] = (bl == ~0ull);
        }
        #pragma unroll
        for (int j = 0; j < 8; j++) {
            int r0 = vs * 16 + j, r1 = vs * 16 + 8 + j;
            unsigned w0 = (u16)v0a[j] | ((unsigned)(u16)v1a[j] << 16);
            unsigned w1 = (u16)v0b[j] | ((unsigned)(u16)v1b[j] << 16);
            *reinterpret_cast<unsigned*>(&Vt[r0 * 64 + (((vp >> 2) ^ (r0 & 7)) << 3) + (vp & 3) * 2]) = w0;
            *reinterpret_cast<unsigned*>(&Vt[r1 * 64 + (((vp >> 2) ^ (r1 & 7)) << 3) + (vp & 3) * 2]) = w1;
        }
        // next iter's B2 orders these writes before their readers
    }

    // --- epilogue: combine pair sums, normalize, store bf16 attended ---
    lrun += __shfl_xor(lrun, 32);
    float inv = 1.f / lrun;
    float invq[16];
    #pragma unroll
    for (int r = 0; r < 16; r++)
        invq[r] = __shfl(inv, (r & 3) + 8 * (r >> 2) + 4 * hi);
    #pragma unroll
    for (int db = 0; db < 4; db++) {
        #pragma unroll
        for (int r = 0; r < 16; r++) {
            int row = qb * 128 + wid * 32 + (r & 3) + 8 * (r >> 2) + 4 * hi;
            int col = h * HD + db * 32 + l31;
            att[(size_t)(b * T_SEQ + row) * D_MODEL + col] = f2bf(oacc[db][r] * invq[r]);
        }
    }
}

// ---------------------------------------------------------------------------
// Launcher
// ---------------------------------------------------------------------------
extern "C" void kernel_launch(void* const* d_in, const int* in_sizes, int n_in,
                              void* d_out, int out_size, void* d_ws, size_t ws_size,
                              hipStream_t stream) {
    (void)in_sizes; (void)n_in; (void)out_size; (void)ws_size;

    const float* x    = (const float*)d_in[0];
    const int*   mask = (const int*)d_in[1];
    const float* Wq   = (const float*)d_in[2];
    const float* bq   = (const float*)d_in[3];
    const float* Wk   = (const float*)d_in[4];
    const float* bk   = (const float*)d_in[5];
    const float* Wv   = (const float*)d_in[6];
    const float* bv   = (const float*)d_in[7];
    const float* Wo   = (const float*)d_in[8];
    const float* bo   = (const float*)d_in[9];
    float* out = (float*)d_out;

    char* ws = (char*)d_ws;
    // workspace layout (bytes):
    u16*   xb   = (u16*)(ws);               // x bf16        8192x2048 : 33,554,432
    u16*   wqkv = (u16*)(ws + 33554432);    // Wq|Wk|Wv bf16 6144x2048 : 25,165,824
    u16*   wo   = (u16*)(ws + 58720256);    // Wo bf16       2048x2048 :  8,388,608
    float* bqkv = (float*)(ws + 67108864);  // bq|bk|bv fp32 6144      :     24,576
    u16*   qkvb = (u16*)(ws + 67133440);    // qkv bf16      8192x6144 :100,663,296
    u16*   attb = (u16*)(ws + 167796736);   // attended bf16 8192x2048 : 33,554,432
                                            // total: 201,351,168 B

    cvt_f32_bf16<<<2048, 256, 0, stream>>>(x,  xb,               16777216 / 8);
    cvt_f32_bf16<<<1024, 256, 0, stream>>>(Wq, wqkv,              4194304 / 8);
    cvt_f32_bf16<<<1024, 256, 0, stream>>>(Wk, wqkv + 4194304,    4194304 / 8);
    cvt_f32_bf16<<<1024, 256, 0, stream>>>(Wv, wqkv + 8388608,    4194304 / 8);
    cvt_f32_bf16<<<1024, 256, 0, stream>>>(Wo, wo,                4194304 / 8);
    hipMemcpyAsync(bqkv,        bq, 2048 * 4, hipMemcpyDeviceToDevice, stream);
    hipMemcpyAsync(bqkv + 2048, bk, 2048 * 4, hipMemcpyDeviceToDevice, stream);
    hipMemcpyAsync(bqkv + 4096, bv, 2048 * 4, hipMemcpyDeviceToDevice, stream);

    const float cs = 0.08838834764831845f * 1.4426950408889634f; // 1/sqrt(128)*log2(e)

    // QKV projection: C[8192][6144] = x * [Wq|Wk|Wv]^T + b   (Q cols pre-scaled by cs)
    gemm_bt<true><<<64 * 48, 256, 0, stream>>>(xb, wqkv, bqkv, qkvb, M_ROWS, N_QKV, D_MODEL, 48, cs, D_MODEL);
    // fused flash attention -> attended bf16 [8192][2048]
    attn<<<1024, 256, 0, stream>>>(qkvb, mask, attb);
    // output projection: out fp32 = attended * Wo^T + bo
    gemm_bt<false><<<64 * 16, 256, 0, stream>>>(attb, wo, bo, out, M_ROWS, D_MODEL, D_MODEL, 16, 1.0f, 0);
}